// Round 4
// baseline (1907.599 us; speedup 1.0000x reference)
//
#include <hip/hip_runtime.h>
#include <cstdint>
#include <cstddef>

#define TAU_D 2.053748910631823
#define M_DIM 8192
#define N_DIM 4096
#define K_DIM 4096
#define NT    (K_DIM / 32)     // 128 K-tiles of BK=32

typedef float f32x4 __attribute__((ext_vector_type(4)));
typedef short bf16x8 __attribute__((ext_vector_type(8)));

typedef __attribute__((address_space(1))) void gvoid_t;
typedef __attribute__((address_space(3))) void lvoid_t;

__device__ __forceinline__ void gload_lds16(const void* g, void* l) {
    __builtin_amdgcn_global_load_lds((const gvoid_t*)g, (lvoid_t*)l, 16, 0, 0);
}

__device__ __forceinline__ unsigned int pack2bf(float lo, float hi) {
    unsigned int ul = __float_as_uint(lo);
    unsigned int uh = __float_as_uint(hi);
    ul = (ul + 0x7FFFu + ((ul >> 16) & 1u)) >> 16;
    uh = (uh + 0x7FFFu + ((uh >> 16) & 1u)) >> 16;
    return ul | (uh << 16);
}

// fp32 -> bf16 (RNE), vectorized: 16B in / 8B out per thread per iter.
__global__ void cvt_f32_to_bf16(const float4* __restrict__ in,
                                uint2* __restrict__ out, int n4) {
    int i = blockIdx.x * blockDim.x + threadIdx.x;
    const int stride = gridDim.x * blockDim.x;
    for (; i < n4; i += stride) {
        float4 a = in[i];
        uint2 o;
        o.x = pack2bf(a.x, a.y);
        o.y = pack2bf(a.z, a.w);
        out[i] = o;
    }
}

// ============================================================================
// 8-phase-style pipelined GEMM: 256x256 tile, BK=32, 8 waves (2Mx4N), 512 thr.
// 3 LDS buffers (stage-ahead = 2 K-tiles, counted vmcnt(4), raw s_barrier).
// Buffer layout (32KB each): [A: 2 halves x 128rows x 64B][B: same] .
// Mask epilogue replicates numpy fp32 sgemm bit-exactly (verified round 3).
// ============================================================================
__global__ __launch_bounds__(512, 2) void gemm_masked8(
    const unsigned short* __restrict__ Ab,   // x bf16 [M][K]
    const unsigned short* __restrict__ Bb,   // W bf16 [N][K]
    const float* __restrict__ X,             // x fp32 (mask)
    const float* __restrict__ Wt,            // W fp32 (mask)
    const float* __restrict__ bias,
    float* __restrict__ out)
{
    __shared__ __align__(16) char lds[98304];   // 3 x 32KB

    const int tid  = threadIdx.x;
    const int wave = tid >> 6;
    const int lane = tid & 63;
    const int lr = lane & 15;
    const int lq = lane >> 4;
    const int wm = wave >> 2;    // 0..1  (row half of 256)
    const int wn = wave & 3;     // 0..3  (64-col slice)

    // XCD-aware swizzle: 512 blocks, 8 XCDs, 512%8==0 -> simple form.
    const int flat = blockIdx.x;
    const int wg = (flat & 7) * 64 + (flat >> 3);
    const int rowBase = (wg >> 4) * 256;   // 32 row-tiles
    const int colBase = (wg & 15) * 256;   // 16 col-tiles

    f32x4 acc[8][4];
    #pragma unroll
    for (int i = 0; i < 8; ++i)
        #pragma unroll
        for (int n = 0; n < 4; ++n)
            acc[i][n] = (f32x4){0.f, 0.f, 0.f, 0.f};

    // ---- staging geometry (linear: flat LDS byte = tid*16 within half) ----
    // half-tile = 128 rows x 32 bf16 (64B rows) = 8KB = 512 thr x 16B.
    const int sr = tid >> 2;          // LDS row 0..127
    const int ss = tid & 3;           // 16B slot 0..3
    const int scol = ss * 8;          // bf16 col within BK=32

    unsigned b0 = 0, b1 = 32768, b2 = 65536;   // rotating buffer offsets

    auto stageA = [&](int t2, int ha, unsigned bo) {
        const unsigned short* src =
            Ab + (size_t)(rowBase + ha * 128 + sr) * K_DIM + t2 * 32 + scol;
        gload_lds16(src, lds + bo + ha * 8192 + wave * 1024);
    };
    auto stageB = [&](int t2, int hb, unsigned bo) {
        const unsigned short* src =
            Bb + (size_t)(colBase + hb * 128 + sr) * K_DIM + t2 * 32 + scol;
        gload_lds16(src, lds + bo + 16384 + hb * 8192 + wave * 1024);
    };

    // ---- ds_read offsets (K-tile independent) ----
    // A: half wm, within-half row r = h*64 + m*16 + lr, slot lq.
    unsigned offA[2][4];
    #pragma unroll
    for (int h = 0; h < 2; ++h)
        #pragma unroll
        for (int m = 0; m < 4; ++m) {
            int r = h * 64 + m * 16 + lr;
            offA[h][m] = wm * 8192 + r * 64 + lq * 16;
        }
    unsigned offB[4];
    #pragma unroll
    for (int n = 0; n < 4; ++n) {
        int rb = (wn & 1) * 64 + n * 16 + lr;
        offB[n] = 16384 + (wn >> 1) * 8192 + rb * 64 + lq * 16;
    }

    // ---- prologue: stage K-tiles 0 (buf0) and 1 (buf1) ----
    stageA(0, 0, b0); stageA(0, 1, b0); stageB(0, 0, b0); stageB(0, 1, b0);
    stageA(1, 0, b1); stageA(1, 1, b1); stageB(1, 0, b1); stageB(1, 1, b1);
    asm volatile("s_waitcnt vmcnt(4)" ::: "memory");   // K0 landed
    __builtin_amdgcn_s_barrier();
    __builtin_amdgcn_sched_barrier(0);

    // ---- main loop: per K-tile, 2 phases of 16 MFMA each ----
    for (int T = 0; T < NT; ++T) {
        const bool st = (T + 2 < NT);

        // ---- phase 0: rows 0-63 of wave block; stage A halves of T+2 ----
        bf16x8 a0[4], bq[4];
        #pragma unroll
        for (int m = 0; m < 4; ++m)
            a0[m] = *(const bf16x8*)(lds + b0 + offA[0][m]);
        #pragma unroll
        for (int n = 0; n < 4; ++n)
            bq[n] = *(const bf16x8*)(lds + b0 + offB[n]);
        if (st) { stageA(T + 2, 0, b2); stageA(T + 2, 1, b2); }
        __builtin_amdgcn_s_barrier();
        __builtin_amdgcn_sched_barrier(0);
        __builtin_amdgcn_s_setprio(1);
        #pragma unroll
        for (int m = 0; m < 4; ++m)
            #pragma unroll
            for (int n = 0; n < 4; ++n)
                acc[m][n] = __builtin_amdgcn_mfma_f32_16x16x32_bf16(
                    a0[m], bq[n], acc[m][n], 0, 0, 0);
        __builtin_amdgcn_s_setprio(0);
        __builtin_amdgcn_s_barrier();
        __builtin_amdgcn_sched_barrier(0);

        // ---- phase 1: rows 64-127; stage B halves of T+2 ----
        bf16x8 a1[4];
        #pragma unroll
        for (int m = 0; m < 4; ++m)
            a1[m] = *(const bf16x8*)(lds + b0 + offA[1][m]);
        if (st) { stageB(T + 2, 0, b2); stageB(T + 2, 1, b2); }
        __builtin_amdgcn_s_barrier();
        __builtin_amdgcn_sched_barrier(0);
        __builtin_amdgcn_s_setprio(1);
        #pragma unroll
        for (int m = 0; m < 4; ++m)
            #pragma unroll
            for (int n = 0; n < 4; ++n)
                acc[4 + m][n] = __builtin_amdgcn_mfma_f32_16x16x32_bf16(
                    a1[m], bq[n], acc[4 + m][n], 0, 0, 0);
        __builtin_amdgcn_s_setprio(0);

        // ---- K-tile boundary: counted vmcnt, then barrier ----
        if (T < NT - 2) {
            asm volatile("s_waitcnt vmcnt(4)" ::: "memory");  // T+1 landed
        } else if (T == NT - 2) {
            asm volatile("s_waitcnt vmcnt(0)" ::: "memory");  // drain tail
        }
        __builtin_amdgcn_s_barrier();
        __builtin_amdgcn_sched_barrier(0);

        unsigned t = b0; b0 = b1; b1 = b2; b2 = t;
    }

    // ---- epilogue: bit-exact fp32 mask + bias + store ----
    float* x0s = (float*)(lds);            // [256][16] f32, 16KB
    float* w0s = (float*)(lds + 16384);    // [256][16] f32
    __syncthreads();
    #pragma unroll
    for (int i = 0; i < 2; ++i) {
        int idx = tid + i * 512;           // 1024 float4 slots
        int r = idx >> 2, qq = (idx & 3) << 2;
        *(f32x4*)(x0s + r * 16 + qq) =
            *(const f32x4*)(X + (size_t)(rowBase + r) * K_DIM + qq);
        *(f32x4*)(w0s + r * 16 + qq) =
            *(const f32x4*)(Wt + (size_t)(colBase + r) * K_DIM + qq);
    }
    __syncthreads();

    const float TAU32 = (float)TAU_D;

    #pragma unroll
    for (int n = 0; n < 4; ++n) {
        const int c = wn * 64 + n * 16 + lr;
        float wv[16];
        #pragma unroll
        for (int q = 0; q < 4; ++q)
            *(f32x4*)&wv[q * 4] = *(const f32x4*)(w0s + c * 16 + q * 4);
        const float bv = bias[colBase + c];
        #pragma unroll
        for (int mi = 0; mi < 8; ++mi) {
            #pragma unroll
            for (int j = 0; j < 4; ++j) {
                const int rw = wm * 128 + mi * 16 + lq * 4 + j;
                float xv[16];
                #pragma unroll
                for (int q = 0; q < 4; ++q)
                    *(f32x4*)&xv[q * 4] = *(const f32x4*)(x0s + rw * 16 + q * 4);
                // Replicate BLAS sgemm: single-acc fma chain, k ascending.
                float y1 = 0.f, s2 = 0.f;
                #pragma unroll
                for (int k = 0; k < 16; ++k) {
                    float xk = xv[k], wk = wv[k];
                    float xx = xk * xk, ww = wk * wk;
                    y1 = fmaf(xk, wk, y1);
                    s2 = fmaf(xx, ww, s2);
                }
                float t = fabsf(y1) / sqrtf(s2 * 0.0625f);
                float v = (t < TAU32) ? 0.0f : (acc[mi][n][j] + bv);
                out[(size_t)(rowBase + rw) * N_DIM + colBase + c] = v;
            }
        }
    }
}

// ============================================================================
// Fallback (no workspace): round-3 verified 128x128 kernel, reg-staged cvt.
// ============================================================================
__global__ __launch_bounds__(256, 2) void gemm_masked_fb(
    const float* __restrict__ X, const float* __restrict__ Wt,
    const float* __restrict__ bias, float* __restrict__ out)
{
    __shared__ __align__(16) unsigned short As[128 * 32];
    __shared__ __align__(16) unsigned short Bs[128 * 32];

    const int tid  = threadIdx.x;
    const int wave = tid >> 6;
    const int lane = tid & 63;
    const int rowBase = blockIdx.y * 128;
    const int colBase = blockIdx.x * 128;
    const int wr = wave >> 1;
    const int wc = wave & 1;
    const int lr = lane & 15;
    const int lq = lane >> 4;

    f32x4 acc[4][4];
    #pragma unroll
    for (int m = 0; m < 4; ++m)
        #pragma unroll
        for (int n = 0; n < 4; ++n)
            acc[m][n] = (f32x4){0.f, 0.f, 0.f, 0.f};

    const int srow = tid >> 2;
    const int scol = (tid & 3) * 8;
    const float* afp = X  + (size_t)(rowBase + srow) * K_DIM + scol;
    const float* bfp = Wt + (size_t)(colBase + srow) * K_DIM + scol;

    for (int kt = 0; kt < K_DIM; kt += 32) {
        #pragma unroll
        for (int issue = 0; issue < 2; ++issue) {
            const float* sa = afp + (size_t)issue * 64 * K_DIM;
            const float* sb = bfp + (size_t)issue * 64 * K_DIM;
            float4 a0 = *(const float4*)(sa);
            float4 a1 = *(const float4*)(sa + 4);
            float4 b0 = *(const float4*)(sb);
            float4 b1 = *(const float4*)(sb + 4);
            uint4 pa, pb;
            pa.x = pack2bf(a0.x, a0.y); pa.y = pack2bf(a0.z, a0.w);
            pa.z = pack2bf(a1.x, a1.y); pa.w = pack2bf(a1.z, a1.w);
            pb.x = pack2bf(b0.x, b0.y); pb.y = pack2bf(b0.z, b0.w);
            pb.z = pack2bf(b1.x, b1.y); pb.w = pack2bf(b1.z, b1.w);
            *(uint4*)((char*)As + issue * 4096 + tid * 16) = pa;
            *(uint4*)((char*)Bs + issue * 4096 + tid * 16) = pb;
        }
        afp += 32; bfp += 32;
        __syncthreads();

        bf16x8 af[4], bq[4];
        #pragma unroll
        for (int m = 0; m < 4; ++m)
            af[m] = *(const bf16x8*)(As + (wr * 64 + m * 16 + lr) * 32 + lq * 8);
        #pragma unroll
        for (int n = 0; n < 4; ++n)
            bq[n] = *(const bf16x8*)(Bs + (wc * 64 + n * 16 + lr) * 32 + lq * 8);
        #pragma unroll
        for (int m = 0; m < 4; ++m)
            #pragma unroll
            for (int n = 0; n < 4; ++n)
                acc[m][n] = __builtin_amdgcn_mfma_f32_16x16x32_bf16(
                    af[m], bq[n], acc[m][n], 0, 0, 0);
        __syncthreads();
    }

    float* x0s = (float*)As;
    float* w0s = (float*)Bs;
    #pragma unroll
    for (int i = 0; i < 2; ++i) {
        int idx = tid + i * 256;
        int r = idx >> 2, q = (idx & 3) * 4;
        *(float4*)(x0s + r * 16 + q) =
            *(const float4*)(X + (size_t)(rowBase + r) * K_DIM + q);
        *(float4*)(w0s + r * 16 + q) =
            *(const float4*)(Wt + (size_t)(colBase + r) * K_DIM + q);
    }
    __syncthreads();

    const float TAU32 = (float)TAU_D;
    float wv[4][16];
    float bv[4];
    #pragma unroll
    for (int n = 0; n < 4; ++n) {
        int c = wc * 64 + n * 16 + lr;
        #pragma unroll
        for (int q = 0; q < 4; ++q)
            *(f32x4*)&wv[n][q * 4] = *(const f32x4*)(w0s + c * 16 + q * 4);
        bv[n] = bias[colBase + c];
    }

    #pragma unroll
    for (int m = 0; m < 4; ++m) {
        #pragma unroll
        for (int j = 0; j < 4; ++j) {
            const int r = wr * 64 + m * 16 + lq * 4 + j;
            float xv[16];
            #pragma unroll
            for (int q = 0; q < 4; ++q)
                *(f32x4*)&xv[q * 4] = *(const f32x4*)(x0s + r * 16 + q * 4);
            const size_t orow = (size_t)(rowBase + r) * N_DIM + colBase;
            #pragma unroll
            for (int n = 0; n < 4; ++n) {
                float y1 = 0.f, s2 = 0.f;
                #pragma unroll
                for (int k = 0; k < 16; ++k) {
                    float xk = xv[k];
                    float wk = wv[n][k];
                    float xx = xk * xk;
                    float ww = wk * wk;
                    y1 = fmaf(xk, wk, y1);
                    s2 = fmaf(xx, ww, s2);
                }
                float t = fabsf(y1) / sqrtf(s2 * 0.0625f);
                float v = (t < TAU32) ? 0.0f : (acc[m][n][j] + bv[n]);
                out[orow + wc * 64 + n * 16 + lr] = v;
            }
        }
    }
}

extern "C" void kernel_launch(void* const* d_in, const int* in_sizes, int n_in,
                              void* d_out, int out_size, void* d_ws, size_t ws_size,
                              hipStream_t stream) {
    const float* x    = (const float*)d_in[0];
    const float* W    = (const float*)d_in[1];
    const float* bias = (const float*)d_in[2];
    float* out = (float*)d_out;

    const size_t needA = (size_t)M_DIM * K_DIM * 2;   // 64 MB
    const size_t needB = (size_t)N_DIM * K_DIM * 2;   // 32 MB

    if (ws_size >= needA + needB) {
        unsigned short* xb = (unsigned short*)d_ws;
        unsigned short* wb = (unsigned short*)((char*)d_ws + needA);
        cvt_f32_to_bf16<<<2048, 256, 0, stream>>>(
            (const float4*)x, (uint2*)xb, (M_DIM * K_DIM) / 4);
        cvt_f32_to_bf16<<<2048, 256, 0, stream>>>(
            (const float4*)W, (uint2*)wb, (N_DIM * K_DIM) / 4);
        dim3 grid((M_DIM / 256) * (N_DIM / 256));     // 512 blocks, 1-D
        gemm_masked8<<<grid, 512, 0, stream>>>(xb, wb, x, W, bias, out);
    } else {
        dim3 grid(N_DIM / 128, M_DIM / 128);
        gemm_masked_fb<<<grid, 256, 0, stream>>>(x, W, bias, out);
    }
}

// Round 5
// 1848.303 us; speedup vs baseline: 1.0321x; 1.0321x over previous
//
#include <hip/hip_runtime.h>
#include <cstdint>
#include <cstddef>

#define TAU_D 2.053748910631823
#define M_DIM 8192
#define N_DIM 4096
#define K_DIM 4096
#define NT64  (K_DIM / 64)     // 64 K-tiles of BK=64

typedef float f32x4 __attribute__((ext_vector_type(4)));
typedef short bf16x8 __attribute__((ext_vector_type(8)));

typedef __attribute__((address_space(1))) void gvoid_t;
typedef __attribute__((address_space(3))) void lvoid_t;

__device__ __forceinline__ void gload_lds16(const void* g, void* l) {
    __builtin_amdgcn_global_load_lds((const gvoid_t*)g, (lvoid_t*)l, 16, 0, 0);
}

__device__ __forceinline__ unsigned int pack2bf(float lo, float hi) {
    unsigned int ul = __float_as_uint(lo);
    unsigned int uh = __float_as_uint(hi);
    ul = (ul + 0x7FFFu + ((ul >> 16) & 1u)) >> 16;
    uh = (uh + 0x7FFFu + ((uh >> 16) & 1u)) >> 16;
    return ul | (uh << 16);
}

// fp32 -> bf16 (RNE), vectorized: 16B in / 8B out per thread per iter.
__global__ void cvt_f32_to_bf16(const float4* __restrict__ in,
                                uint2* __restrict__ out, int n4) {
    int i = blockIdx.x * blockDim.x + threadIdx.x;
    const int stride = gridDim.x * blockDim.x;
    for (; i < n4; i += stride) {
        float4 a = in[i];
        uint2 o;
        o.x = pack2bf(a.x, a.y);
        o.y = pack2bf(a.z, a.w);
        out[i] = o;
    }
}

// ============================================================================
// 256x256 tile, BK=64, 8 waves (2Mx4N), 512 thr, 2 LDS buffers (128KB).
// 4 phases/K-tile (quadrant = m-half x k-half), stage A(T+1)@ph1, B(T+1)@ph2,
// one __syncthreads boundary per tile (loads aged 2-3 phases by then).
// T2 XOR-swizzle: phys 16B-slot = logical_slot ^ (row&7); linear LDS dest +
// pre-swizzled GLOBAL source (rule 21) + swizzled ds_read (lane-const XOR).
// XCD map: each XCD owns 2 col-panels sequentially -> B L2-hot (2MB/XCD).
// Mask epilogue replicates numpy fp32 sgemm bit-exactly (verified rounds 3/4).
// ============================================================================
__global__ __launch_bounds__(512, 2) void gemm_masked8(
    const unsigned short* __restrict__ Ab,   // x bf16 [M][K]
    const unsigned short* __restrict__ Bb,   // W bf16 [N][K]
    const float* __restrict__ X,             // x fp32 (mask)
    const float* __restrict__ Wt,            // W fp32 (mask)
    const float* __restrict__ bias,
    float* __restrict__ out)
{
    __shared__ __align__(16) char lds[131072];   // 2 x (A 32KB + B 32KB)

    const int tid  = threadIdx.x;
    const int wave = tid >> 6;
    const int lane = tid & 63;
    const int lr = lane & 15;
    const int lq = lane >> 4;
    const int wm = wave >> 2;    // 0..1 : row half (128 rows)
    const int wn = wave & 3;     // 0..3 : 64-col slice

    // XCD col-panel map: XCD k (=flat%8) owns wg [k*64,(k+1)*64) = cols {2k,2k+1}.
    const int flat = blockIdx.x;
    const int wg = (flat & 7) * 64 + (flat >> 3);
    const int rowBase = (wg & 31) * 256;   // 32 row-tiles
    const int colBase = (wg >> 5) * 256;   // 16 col-tiles

    f32x4 acc[8][4];
    #pragma unroll
    for (int i = 0; i < 8; ++i)
        #pragma unroll
        for (int n = 0; n < 4; ++n)
            acc[i][n] = (f32x4){0.f, 0.f, 0.f, 0.f};

    // ---- staging sources (pre-swizzled global column; LDS dest linear) ----
    // gload instr i: LDS flat byte = opBase + i*8192 + tid*16
    //   -> row = i*64 + (tid>>3), phys slot = tid&7.
    // logical slot to fetch there = (tid&7) ^ (row&7) = (tid&7) ^ ((tid>>3)&7).
    const int srow  = tid >> 3;                       // 0..63
    const int sslot = (tid & 7) ^ (srow & 7);
    const unsigned short* aSrc =
        Ab + (size_t)(rowBase + srow) * K_DIM + sslot * 8;
    const unsigned short* bSrc =
        Bb + (size_t)(colBase + srow) * K_DIM + sslot * 8;

    // ---- ds_read byte offsets: row*128 + ((ks*4+lq)^(lr&7))*16 ----
    const unsigned baseA = (unsigned)(wm * 128 + lr) * 128;
    const unsigned baseB = 32768u + (unsigned)(wn * 64 + lr) * 128;
    const unsigned sk0 = (unsigned)((lq) ^ (lr & 7)) * 16;
    const unsigned sk1 = (unsigned)((4 + lq) ^ (lr & 7)) * 16;

    // ---- prologue: stage K-tile 0 into buffer 0 ----
    #pragma unroll
    for (int i = 0; i < 4; ++i)
        gload_lds16(aSrc + (size_t)i * 64 * K_DIM,
                    lds + i * 8192 + wave * 1024);
    #pragma unroll
    for (int i = 0; i < 4; ++i)
        gload_lds16(bSrc + (size_t)i * 64 * K_DIM,
                    lds + 32768 + i * 8192 + wave * 1024);
    __syncthreads();

    for (int T = 0; T < NT64; ++T) {
        const bool st = (T + 1 < NT64);
        const unsigned cb = (unsigned)(T & 1) << 16;   // 0 / 65536
        const unsigned ob = cb ^ 65536u;
        const char* L = lds + cb;
        const unsigned short* aS = aSrc + (size_t)(T + 1) * 64;
        const unsigned short* bS = bSrc + (size_t)(T + 1) * 64;

        bf16x8 af[4], bq[4];

        // ---------- phase 1: (m 0-3, ks 0); stage A(T+1) ----------
        #pragma unroll
        for (int m = 0; m < 4; ++m)
            af[m] = *(const bf16x8*)(L + baseA + m * 2048 + sk0);
        #pragma unroll
        for (int n = 0; n < 4; ++n)
            bq[n] = *(const bf16x8*)(L + baseB + n * 2048 + sk0);
        if (st) {
            #pragma unroll
            for (int i = 0; i < 4; ++i)
                gload_lds16(aS + (size_t)i * 64 * K_DIM,
                            lds + ob + i * 8192 + wave * 1024);
        }
        __builtin_amdgcn_s_barrier();
        __builtin_amdgcn_sched_barrier(0);
        __builtin_amdgcn_s_setprio(1);
        #pragma unroll
        for (int m = 0; m < 4; ++m)
            #pragma unroll
            for (int n = 0; n < 4; ++n)
                acc[m][n] = __builtin_amdgcn_mfma_f32_16x16x32_bf16(
                    af[m], bq[n], acc[m][n], 0, 0, 0);
        __builtin_amdgcn_s_setprio(0);
        __builtin_amdgcn_s_barrier();
        __builtin_amdgcn_sched_barrier(0);

        // ---------- phase 2: (m 4-7, ks 0); stage B(T+1) ----------
        #pragma unroll
        for (int m = 0; m < 4; ++m)
            af[m] = *(const bf16x8*)(L + baseA + (4 + m) * 2048 + sk0);
        if (st) {
            #pragma unroll
            for (int i = 0; i < 4; ++i)
                gload_lds16(bS + (size_t)i * 64 * K_DIM,
                            lds + ob + 32768 + i * 8192 + wave * 1024);
        }
        __builtin_amdgcn_s_barrier();
        __builtin_amdgcn_sched_barrier(0);
        __builtin_amdgcn_s_setprio(1);
        #pragma unroll
        for (int m = 0; m < 4; ++m)
            #pragma unroll
            for (int n = 0; n < 4; ++n)
                acc[4 + m][n] = __builtin_amdgcn_mfma_f32_16x16x32_bf16(
                    af[m], bq[n], acc[4 + m][n], 0, 0, 0);
        __builtin_amdgcn_s_setprio(0);
        __builtin_amdgcn_s_barrier();
        __builtin_amdgcn_sched_barrier(0);

        // ---------- phase 3: (m 0-3, ks 1) ----------
        #pragma unroll
        for (int m = 0; m < 4; ++m)
            af[m] = *(const bf16x8*)(L + baseA + m * 2048 + sk1);
        #pragma unroll
        for (int n = 0; n < 4; ++n)
            bq[n] = *(const bf16x8*)(L + baseB + n * 2048 + sk1);
        __builtin_amdgcn_s_barrier();
        __builtin_amdgcn_sched_barrier(0);
        __builtin_amdgcn_s_setprio(1);
        #pragma unroll
        for (int m = 0; m < 4; ++m)
            #pragma unroll
            for (int n = 0; n < 4; ++n)
                acc[m][n] = __builtin_amdgcn_mfma_f32_16x16x32_bf16(
                    af[m], bq[n], acc[m][n], 0, 0, 0);
        __builtin_amdgcn_s_setprio(0);
        __builtin_amdgcn_s_barrier();
        __builtin_amdgcn_sched_barrier(0);

        // ---------- phase 4: (m 4-7, ks 1) ----------
        #pragma unroll
        for (int m = 0; m < 4; ++m)
            af[m] = *(const bf16x8*)(L + baseA + (4 + m) * 2048 + sk1);
        __builtin_amdgcn_s_barrier();
        __builtin_amdgcn_sched_barrier(0);
        __builtin_amdgcn_s_setprio(1);
        #pragma unroll
        for (int m = 0; m < 4; ++m)
            #pragma unroll
            for (int n = 0; n < 4; ++n)
                acc[4 + m][n] = __builtin_amdgcn_mfma_f32_16x16x32_bf16(
                    af[m], bq[n], acc[4 + m][n], 0, 0, 0);
        __builtin_amdgcn_s_setprio(0);

        // ---------- boundary: full drain (T+1's loads aged 2-3 phases) ----
        __syncthreads();
    }

    // ---- epilogue: bit-exact fp32 mask + bias + store (verified r3/r4) ----
    float* x0s = (float*)(lds);            // [256][16] f32, 16KB
    float* w0s = (float*)(lds + 16384);    // [256][16] f32
    #pragma unroll
    for (int i = 0; i < 2; ++i) {
        int idx = tid + i * 512;           // 1024 float4 slots
        int r = idx >> 2, qq = (idx & 3) << 2;
        *(f32x4*)(x0s + r * 16 + qq) =
            *(const f32x4*)(X + (size_t)(rowBase + r) * K_DIM + qq);
        *(f32x4*)(w0s + r * 16 + qq) =
            *(const f32x4*)(Wt + (size_t)(colBase + r) * K_DIM + qq);
    }
    __syncthreads();

    const float TAU32 = (float)TAU_D;

    #pragma unroll
    for (int n = 0; n < 4; ++n) {
        const int c = wn * 64 + n * 16 + lr;
        float wv[16];
        #pragma unroll
        for (int q = 0; q < 4; ++q)
            *(f32x4*)&wv[q * 4] = *(const f32x4*)(w0s + c * 16 + q * 4);
        const float bv = bias[colBase + c];
        #pragma unroll
        for (int mi = 0; mi < 8; ++mi) {
            #pragma unroll
            for (int j = 0; j < 4; ++j) {
                const int rw = wm * 128 + mi * 16 + lq * 4 + j;
                float xv[16];
                #pragma unroll
                for (int q = 0; q < 4; ++q)
                    *(f32x4*)&xv[q * 4] = *(const f32x4*)(x0s + rw * 16 + q * 4);
                // Replicate BLAS sgemm: single-acc fma chain, k ascending.
                float y1 = 0.f, s2 = 0.f;
                #pragma unroll
                for (int k = 0; k < 16; ++k) {
                    float xk = xv[k], wk = wv[k];
                    float xx = xk * xk, ww = wk * wk;
                    y1 = fmaf(xk, wk, y1);
                    s2 = fmaf(xx, ww, s2);
                }
                float t = fabsf(y1) / sqrtf(s2 * 0.0625f);
                float v = (t < TAU32) ? 0.0f : (acc[mi][n][j] + bv);
                out[(size_t)(rowBase + rw) * N_DIM + colBase + c] = v;
            }
        }
    }
}

// ============================================================================
// Fallback (no workspace): round-3 verified 128x128 kernel, reg-staged cvt.
// ============================================================================
__global__ __launch_bounds__(256, 2) void gemm_masked_fb(
    const float* __restrict__ X, const float* __restrict__ Wt,
    const float* __restrict__ bias, float* __restrict__ out)
{
    __shared__ __align__(16) unsigned short As[128 * 32];
    __shared__ __align__(16) unsigned short Bs[128 * 32];

    const int tid  = threadIdx.x;
    const int wave = tid >> 6;
    const int lane = tid & 63;
    const int rowBase = blockIdx.y * 128;
    const int colBase = blockIdx.x * 128;
    const int wr = wave >> 1;
    const int wc = wave & 1;
    const int lr = lane & 15;
    const int lq = lane >> 4;

    f32x4 acc[4][4];
    #pragma unroll
    for (int m = 0; m < 4; ++m)
        #pragma unroll
        for (int n = 0; n < 4; ++n)
            acc[m][n] = (f32x4){0.f, 0.f, 0.f, 0.f};

    const int srow = tid >> 2;
    const int scol = (tid & 3) * 8;
    const float* afp = X  + (size_t)(rowBase + srow) * K_DIM + scol;
    const float* bfp = Wt + (size_t)(colBase + srow) * K_DIM + scol;

    for (int kt = 0; kt < K_DIM; kt += 32) {
        #pragma unroll
        for (int issue = 0; issue < 2; ++issue) {
            const float* sa = afp + (size_t)issue * 64 * K_DIM;
            const float* sb = bfp + (size_t)issue * 64 * K_DIM;
            float4 a0 = *(const float4*)(sa);
            float4 a1 = *(const float4*)(sa + 4);
            float4 b0 = *(const float4*)(sb);
            float4 b1 = *(const float4*)(sb + 4);
            uint4 pa, pb;
            pa.x = pack2bf(a0.x, a0.y); pa.y = pack2bf(a0.z, a0.w);
            pa.z = pack2bf(a1.x, a1.y); pa.w = pack2bf(a1.z, a1.w);
            pb.x = pack2bf(b0.x, b0.y); pb.y = pack2bf(b0.z, b0.w);
            pb.z = pack2bf(b1.x, b1.y); pb.w = pack2bf(b1.z, b1.w);
            *(uint4*)((char*)As + issue * 4096 + tid * 16) = pa;
            *(uint4*)((char*)Bs + issue * 4096 + tid * 16) = pb;
        }
        afp += 32; bfp += 32;
        __syncthreads();

        bf16x8 af[4], bq[4];
        #pragma unroll
        for (int m = 0; m < 4; ++m)
            af[m] = *(const bf16x8*)(As + (wr * 64 + m * 16 + lr) * 32 + lq * 8);
        #pragma unroll
        for (int n = 0; n < 4; ++n)
            bq[n] = *(const bf16x8*)(Bs + (wc * 64 + n * 16 + lr) * 32 + lq * 8);
        #pragma unroll
        for (int m = 0; m < 4; ++m)
            #pragma unroll
            for (int n = 0; n < 4; ++n)
                acc[m][n] = __builtin_amdgcn_mfma_f32_16x16x32_bf16(
                    af[m], bq[n], acc[m][n], 0, 0, 0);
        __syncthreads();
    }

    float* x0s = (float*)As;
    float* w0s = (float*)Bs;
    #pragma unroll
    for (int i = 0; i < 2; ++i) {
        int idx = tid + i * 256;
        int r = idx >> 2, q = (idx & 3) * 4;
        *(float4*)(x0s + r * 16 + q) =
            *(const float4*)(X + (size_t)(rowBase + r) * K_DIM + q);
        *(float4*)(w0s + r * 16 + q) =
            *(const float4*)(Wt + (size_t)(colBase + r) * K_DIM + q);
    }
    __syncthreads();

    const float TAU32 = (float)TAU_D;
    float wv[4][16];
    float bv[4];
    #pragma unroll
    for (int n = 0; n < 4; ++n) {
        int c = wc * 64 + n * 16 + lr;
        #pragma unroll
        for (int q = 0; q < 4; ++q)
            *(f32x4*)&wv[n][q * 4] = *(const f32x4*)(w0s + c * 16 + q * 4);
        bv[n] = bias[colBase + c];
    }

    #pragma unroll
    for (int m = 0; m < 4; ++m) {
        #pragma unroll
        for (int j = 0; j < 4; ++j) {
            const int r = wr * 64 + m * 16 + lq * 4 + j;
            float xv[16];
            #pragma unroll
            for (int q = 0; q < 4; ++q)
                *(f32x4*)&xv[q * 4] = *(const f32x4*)(x0s + r * 16 + q * 4);
            const size_t orow = (size_t)(rowBase + r) * N_DIM + colBase;
            #pragma unroll
            for (int n = 0; n < 4; ++n) {
                float y1 = 0.f, s2 = 0.f;
                #pragma unroll
                for (int k = 0; k < 16; ++k) {
                    float xk = xv[k];
                    float wk = wv[n][k];
                    float xx = xk * xk;
                    float ww = wk * wk;
                    y1 = fmaf(xk, wk, y1);
                    s2 = fmaf(xx, ww, s2);
                }
                float t = fabsf(y1) / sqrtf(s2 * 0.0625f);
                float v = (t < TAU32) ? 0.0f : (acc[m][n][j] + bv[n]);
                out[orow + wc * 64 + n * 16 + lr] = v;
            }
        }
    }
}

extern "C" void kernel_launch(void* const* d_in, const int* in_sizes, int n_in,
                              void* d_out, int out_size, void* d_ws, size_t ws_size,
                              hipStream_t stream) {
    const float* x    = (const float*)d_in[0];
    const float* W    = (const float*)d_in[1];
    const float* bias = (const float*)d_in[2];
    float* out = (float*)d_out;

    const size_t needA = (size_t)M_DIM * K_DIM * 2;   // 64 MB
    const size_t needB = (size_t)N_DIM * K_DIM * 2;   // 32 MB

    if (ws_size >= needA + needB) {
        unsigned short* xb = (unsigned short*)d_ws;
        unsigned short* wb = (unsigned short*)((char*)d_ws + needA);
        cvt_f32_to_bf16<<<2048, 256, 0, stream>>>(
            (const float4*)x, (uint2*)xb, (M_DIM * K_DIM) / 4);
        cvt_f32_to_bf16<<<2048, 256, 0, stream>>>(
            (const float4*)W, (uint2*)wb, (N_DIM * K_DIM) / 4);
        dim3 grid((M_DIM / 256) * (N_DIM / 256));     // 512 blocks, 1-D
        gemm_masked8<<<grid, 512, 0, stream>>>(xb, wb, x, W, bias, out);
    } else {
        dim3 grid(N_DIM / 128, M_DIM / 128);
        gemm_masked_fb<<<grid, 256, 0, stream>>>(x, W, bias, out);
    }
}

// Round 6
// 331.163 us; speedup vs baseline: 5.7603x; 5.5813x over previous
//
#include <hip/hip_runtime.h>
#include <cstdint>
#include <cstddef>

#define TAU_D 2.053748910631823
#define M_DIM 8192
#define N_DIM 4096
#define K_DIM 4096
#define NT64  (K_DIM / 64)     // 64 K-tiles of BK=64

typedef float f32x4 __attribute__((ext_vector_type(4)));
typedef short bf16x8 __attribute__((ext_vector_type(8)));

typedef __attribute__((address_space(1))) void gvoid_t;
typedef __attribute__((address_space(3))) void lvoid_t;

__device__ __forceinline__ void gload_lds16(const void* g, void* l) {
    __builtin_amdgcn_global_load_lds((const gvoid_t*)g, (lvoid_t*)l, 16, 0, 0);
}

__device__ __forceinline__ unsigned int pack2bf(float lo, float hi) {
    unsigned int ul = __float_as_uint(lo);
    unsigned int uh = __float_as_uint(hi);
    ul = (ul + 0x7FFFu + ((ul >> 16) & 1u)) >> 16;
    uh = (uh + 0x7FFFu + ((uh >> 16) & 1u)) >> 16;
    return ul | (uh << 16);
}

// fp32 -> bf16 (RNE), vectorized: 16B in / 8B out per thread per iter.
__global__ void cvt_f32_to_bf16(const float4* __restrict__ in,
                                uint2* __restrict__ out, int n4) {
    int i = blockIdx.x * blockDim.x + threadIdx.x;
    const int stride = gridDim.x * blockDim.x;
    for (; i < n4; i += stride) {
        float4 a = in[i];
        uint2 o;
        o.x = pack2bf(a.x, a.y);
        o.y = pack2bf(a.z, a.w);
        out[i] = o;
    }
}

// ============================================================================
// 256x256 tile, BK=64, 8 waves (2Mx4N), 512 thr, 2 LDS buffers (128KB).
// 4 phases/K-tile; stage A(T+1)@ph1, B(T+1)@ph2; full drain at tile boundary
// (loads get ~3 phases + the whole next-issue window of cover).
// T2 XOR-swizzle: phys 16B-slot = logical_slot ^ (row&7); linear LDS dest +
// pre-swizzled GLOBAL source (rule 21) + swizzled ds_read (lane-const XOR).
// XCD map (concurrency-aware): with 1 block/CU, XCD k's concurrent 32 blocks
// (flat = k, k+8, ...) form an 8-tile-row x 4-tile-col cluster -> per-K-step
// L2 working set 384KB; A lines reused 4x, B lines 8x within the XCD's L2.
// Epilogue: n-paired stores complete each 128B line back-to-back (write amp
// fix); mask replicates numpy fp32 sgemm bit-exactly (verified rounds 3-5).
// ============================================================================
__global__ __launch_bounds__(512, 2) void gemm_masked8(
    const unsigned short* __restrict__ Ab,   // x bf16 [M][K]
    const unsigned short* __restrict__ Bb,   // W bf16 [N][K]
    const float* __restrict__ X,             // x fp32 (mask)
    const float* __restrict__ Wt,            // W fp32 (mask)
    const float* __restrict__ bias,
    float* __restrict__ out)
{
    __shared__ __align__(16) char lds[131072];   // 2 x (A 32KB + B 32KB)

    const int tid  = threadIdx.x;
    const int wave = tid >> 6;
    const int lane = tid & 63;
    const int lr = lane & 15;
    const int lq = lane >> 4;
    const int wm = wave >> 2;    // 0..1 : row half (128 rows)
    const int wn = wave & 3;     // 0..3 : 64-col slice

    // Concurrency-aware XCD cluster map (512 blocks, 1 block/CU, 2 rounds):
    //   xcd = flat&7 owns slots s = flat>>3; round = s>>5, j = s&31.
    //   Cluster: 8 tile-rows x 4 tile-cols per XCD per round. Bijective.
    const int flat = blockIdx.x;
    const int xcd  = flat & 7;
    const int s    = flat >> 3;            // 0..63
    const int rnd  = s >> 5;               // 0..1
    const int jj   = s & 31;               // 0..31
    const int trow = rnd * 16 + ((xcd >> 2) << 3) + (jj >> 2);   // 0..31
    const int tcol = ((xcd & 3) << 2) + (jj & 3);                // 0..15
    const int rowBase = trow * 256;
    const int colBase = tcol * 256;

    f32x4 acc[8][4];
    #pragma unroll
    for (int i = 0; i < 8; ++i)
        #pragma unroll
        for (int n = 0; n < 4; ++n)
            acc[i][n] = (f32x4){0.f, 0.f, 0.f, 0.f};

    // ---- staging sources (pre-swizzled global column; LDS dest linear) ----
    // gload instr i: LDS flat byte = opBase + i*8192 + tid*16
    //   -> row = i*64 + (tid>>3), phys slot = tid&7.
    // logical slot to fetch there = (tid&7) ^ (row&7) = (tid&7) ^ ((tid>>3)&7).
    const int srow  = tid >> 3;                       // 0..63
    const int sslot = (tid & 7) ^ (srow & 7);
    const unsigned short* aSrc =
        Ab + (size_t)(rowBase + srow) * K_DIM + sslot * 8;
    const unsigned short* bSrc =
        Bb + (size_t)(colBase + srow) * K_DIM + sslot * 8;

    // ---- ds_read byte offsets: row*128 + ((ks*4+lq)^(lr&7))*16 ----
    const unsigned baseA = (unsigned)(wm * 128 + lr) * 128;
    const unsigned baseB = 32768u + (unsigned)(wn * 64 + lr) * 128;
    const unsigned sk0 = (unsigned)((lq) ^ (lr & 7)) * 16;
    const unsigned sk1 = (unsigned)((4 + lq) ^ (lr & 7)) * 16;

    // ---- prologue: stage K-tile 0 into buffer 0 ----
    #pragma unroll
    for (int i = 0; i < 4; ++i)
        gload_lds16(aSrc + (size_t)i * 64 * K_DIM,
                    lds + i * 8192 + wave * 1024);
    #pragma unroll
    for (int i = 0; i < 4; ++i)
        gload_lds16(bSrc + (size_t)i * 64 * K_DIM,
                    lds + 32768 + i * 8192 + wave * 1024);
    __syncthreads();

    for (int T = 0; T < NT64; ++T) {
        const bool st = (T + 1 < NT64);
        const unsigned cb = (unsigned)(T & 1) << 16;   // 0 / 65536
        const unsigned ob = cb ^ 65536u;
        const char* L = lds + cb;
        const unsigned short* aS = aSrc + (size_t)(T + 1) * 64;
        const unsigned short* bS = bSrc + (size_t)(T + 1) * 64;

        bf16x8 af[4], bq[4];

        // ---------- phase 1: (m 0-3, ks 0); stage A(T+1) ----------
        #pragma unroll
        for (int m = 0; m < 4; ++m)
            af[m] = *(const bf16x8*)(L + baseA + m * 2048 + sk0);
        #pragma unroll
        for (int n = 0; n < 4; ++n)
            bq[n] = *(const bf16x8*)(L + baseB + n * 2048 + sk0);
        if (st) {
            #pragma unroll
            for (int i = 0; i < 4; ++i)
                gload_lds16(aS + (size_t)i * 64 * K_DIM,
                            lds + ob + i * 8192 + wave * 1024);
        }
        __builtin_amdgcn_s_barrier();
        __builtin_amdgcn_sched_barrier(0);
        __builtin_amdgcn_s_setprio(1);
        #pragma unroll
        for (int m = 0; m < 4; ++m)
            #pragma unroll
            for (int n = 0; n < 4; ++n)
                acc[m][n] = __builtin_amdgcn_mfma_f32_16x16x32_bf16(
                    af[m], bq[n], acc[m][n], 0, 0, 0);
        __builtin_amdgcn_s_setprio(0);
        __builtin_amdgcn_s_barrier();
        __builtin_amdgcn_sched_barrier(0);

        // ---------- phase 2: (m 4-7, ks 0); stage B(T+1) ----------
        #pragma unroll
        for (int m = 0; m < 4; ++m)
            af[m] = *(const bf16x8*)(L + baseA + (4 + m) * 2048 + sk0);
        if (st) {
            #pragma unroll
            for (int i = 0; i < 4; ++i)
                gload_lds16(bS + (size_t)i * 64 * K_DIM,
                            lds + ob + 32768 + i * 8192 + wave * 1024);
        }
        __builtin_amdgcn_s_barrier();
        __builtin_amdgcn_sched_barrier(0);
        __builtin_amdgcn_s_setprio(1);
        #pragma unroll
        for (int m = 0; m < 4; ++m)
            #pragma unroll
            for (int n = 0; n < 4; ++n)
                acc[4 + m][n] = __builtin_amdgcn_mfma_f32_16x16x32_bf16(
                    af[m], bq[n], acc[4 + m][n], 0, 0, 0);
        __builtin_amdgcn_s_setprio(0);
        __builtin_amdgcn_s_barrier();
        __builtin_amdgcn_sched_barrier(0);

        // ---------- phase 3: (m 0-3, ks 1) ----------
        #pragma unroll
        for (int m = 0; m < 4; ++m)
            af[m] = *(const bf16x8*)(L + baseA + m * 2048 + sk1);
        #pragma unroll
        for (int n = 0; n < 4; ++n)
            bq[n] = *(const bf16x8*)(L + baseB + n * 2048 + sk1);
        __builtin_amdgcn_s_barrier();
        __builtin_amdgcn_sched_barrier(0);
        __builtin_amdgcn_s_setprio(1);
        #pragma unroll
        for (int m = 0; m < 4; ++m)
            #pragma unroll
            for (int n = 0; n < 4; ++n)
                acc[m][n] = __builtin_amdgcn_mfma_f32_16x16x32_bf16(
                    af[m], bq[n], acc[m][n], 0, 0, 0);
        __builtin_amdgcn_s_setprio(0);
        __builtin_amdgcn_s_barrier();
        __builtin_amdgcn_sched_barrier(0);

        // ---------- phase 4: (m 4-7, ks 1) ----------
        #pragma unroll
        for (int m = 0; m < 4; ++m)
            af[m] = *(const bf16x8*)(L + baseA + (4 + m) * 2048 + sk1);
        __builtin_amdgcn_s_barrier();
        __builtin_amdgcn_sched_barrier(0);
        __builtin_amdgcn_s_setprio(1);
        #pragma unroll
        for (int m = 0; m < 4; ++m)
            #pragma unroll
            for (int n = 0; n < 4; ++n)
                acc[4 + m][n] = __builtin_amdgcn_mfma_f32_16x16x32_bf16(
                    af[m], bq[n], acc[4 + m][n], 0, 0, 0);
        __builtin_amdgcn_s_setprio(0);

        // ---------- boundary: full drain (next tile's data must be ready) --
        __syncthreads();
    }

    // ---- epilogue: bit-exact fp32 mask + bias + store (verified r3-r5) ----
    float* x0s = (float*)(lds);            // [256][16] f32, 16KB
    float* w0s = (float*)(lds + 16384);    // [256][16] f32
    #pragma unroll
    for (int i = 0; i < 2; ++i) {
        int idx = tid + i * 512;           // 1024 float4 slots
        int r = idx >> 2, qq = (idx & 3) << 2;
        *(f32x4*)(x0s + r * 16 + qq) =
            *(const f32x4*)(X + (size_t)(rowBase + r) * K_DIM + qq);
        *(f32x4*)(w0s + r * 16 + qq) =
            *(const f32x4*)(Wt + (size_t)(colBase + r) * K_DIM + qq);
    }
    __syncthreads();

    const float TAU32 = (float)TAU_D;

    // n processed in adjacent pairs so both 64B halves of each 128B output
    // line are stored back-to-back (kills the r4/r5 write amplification).
    #pragma unroll
    for (int np = 0; np < 4; np += 2) {
        float wv[2][16];
        float bv[2];
        #pragma unroll
        for (int e = 0; e < 2; ++e) {
            const int c = wn * 64 + (np + e) * 16 + lr;
            #pragma unroll
            for (int q = 0; q < 4; ++q)
                *(f32x4*)&wv[e][q * 4] = *(const f32x4*)(w0s + c * 16 + q * 4);
            bv[e] = bias[colBase + c];
        }
        #pragma unroll
        for (int mi = 0; mi < 8; ++mi) {
            #pragma unroll
            for (int j = 0; j < 4; ++j) {
                const int rw = wm * 128 + mi * 16 + lq * 4 + j;
                float xv[16];
                #pragma unroll
                for (int q = 0; q < 4; ++q)
                    *(f32x4*)&xv[q * 4] = *(const f32x4*)(x0s + rw * 16 + q * 4);
                const size_t orow = (size_t)(rowBase + rw) * N_DIM + colBase;
                #pragma unroll
                for (int e = 0; e < 2; ++e) {
                    const int n = np + e;
                    // Replicate BLAS sgemm: single-acc fma chain, k ascending.
                    float y1 = 0.f, s2 = 0.f;
                    #pragma unroll
                    for (int k = 0; k < 16; ++k) {
                        float xk = xv[k], wk = wv[e][k];
                        float xx = xk * xk, ww = wk * wk;
                        y1 = fmaf(xk, wk, y1);
                        s2 = fmaf(xx, ww, s2);
                    }
                    float t = fabsf(y1) / sqrtf(s2 * 0.0625f);
                    float v = (t < TAU32) ? 0.0f : (acc[mi][n][j] + bv[e]);
                    out[orow + wn * 64 + n * 16 + lr] = v;
                }
            }
        }
    }
}

// ============================================================================
// Fallback (no workspace): round-3 verified 128x128 kernel, reg-staged cvt.
// ============================================================================
__global__ __launch_bounds__(256, 2) void gemm_masked_fb(
    const float* __restrict__ X, const float* __restrict__ Wt,
    const float* __restrict__ bias, float* __restrict__ out)
{
    __shared__ __align__(16) unsigned short As[128 * 32];
    __shared__ __align__(16) unsigned short Bs[128 * 32];

    const int tid  = threadIdx.x;
    const int wave = tid >> 6;
    const int lane = tid & 63;
    const int rowBase = blockIdx.y * 128;
    const int colBase = blockIdx.x * 128;
    const int wr = wave >> 1;
    const int wc = wave & 1;
    const int lr = lane & 15;
    const int lq = lane >> 4;

    f32x4 acc[4][4];
    #pragma unroll
    for (int m = 0; m < 4; ++m)
        #pragma unroll
        for (int n = 0; n < 4; ++n)
            acc[m][n] = (f32x4){0.f, 0.f, 0.f, 0.f};

    const int srow = tid >> 2;
    const int scol = (tid & 3) * 8;
    const float* afp = X  + (size_t)(rowBase + srow) * K_DIM + scol;
    const float* bfp = Wt + (size_t)(colBase + srow) * K_DIM + scol;

    for (int kt = 0; kt < K_DIM; kt += 32) {
        #pragma unroll
        for (int issue = 0; issue < 2; ++issue) {
            const float* sa = afp + (size_t)issue * 64 * K_DIM;
            const float* sb = bfp + (size_t)issue * 64 * K_DIM;
            float4 a0 = *(const float4*)(sa);
            float4 a1 = *(const float4*)(sa + 4);
            float4 b0 = *(const float4*)(sb);
            float4 b1 = *(const float4*)(sb + 4);
            uint4 pa, pb;
            pa.x = pack2bf(a0.x, a0.y); pa.y = pack2bf(a0.z, a0.w);
            pa.z = pack2bf(a1.x, a1.y); pa.w = pack2bf(a1.z, a1.w);
            pb.x = pack2bf(b0.x, b0.y); pb.y = pack2bf(b0.z, b0.w);
            pb.z = pack2bf(b1.x, b1.y); pb.w = pack2bf(b1.z, b1.w);
            *(uint4*)((char*)As + issue * 4096 + tid * 16) = pa;
            *(uint4*)((char*)Bs + issue * 4096 + tid * 16) = pb;
        }
        afp += 32; bfp += 32;
        __syncthreads();

        bf16x8 af[4], bq[4];
        #pragma unroll
        for (int m = 0; m < 4; ++m)
            af[m] = *(const bf16x8*)(As + (wr * 64 + m * 16 + lr) * 32 + lq * 8);
        #pragma unroll
        for (int n = 0; n < 4; ++n)
            bq[n] = *(const bf16x8*)(Bs + (wc * 64 + n * 16 + lr) * 32 + lq * 8);
        #pragma unroll
        for (int m = 0; m < 4; ++m)
            #pragma unroll
            for (int n = 0; n < 4; ++n)
                acc[m][n] = __builtin_amdgcn_mfma_f32_16x16x32_bf16(
                    af[m], bq[n], acc[m][n], 0, 0, 0);
        __syncthreads();
    }

    float* x0s = (float*)As;
    float* w0s = (float*)Bs;
    #pragma unroll
    for (int i = 0; i < 2; ++i) {
        int idx = tid + i * 256;
        int r = idx >> 2, q = (idx & 3) * 4;
        *(float4*)(x0s + r * 16 + q) =
            *(const float4*)(X + (size_t)(rowBase + r) * K_DIM + q);
        *(float4*)(w0s + r * 16 + q) =
            *(const float4*)(Wt + (size_t)(colBase + r) * K_DIM + q);
    }
    __syncthreads();

    const float TAU32 = (float)TAU_D;
    float wv[4][16];
    float bv[4];
    #pragma unroll
    for (int n = 0; n < 4; ++n) {
        int c = wc * 64 + n * 16 + lr;
        #pragma unroll
        for (int q = 0; q < 4; ++q)
            *(f32x4*)&wv[n][q * 4] = *(const f32x4*)(w0s + c * 16 + q * 4);
        bv[n] = bias[colBase + c];
    }

    #pragma unroll
    for (int m = 0; m < 4; ++m) {
        #pragma unroll
        for (int j = 0; j < 4; ++j) {
            const int r = wr * 64 + m * 16 + lq * 4 + j;
            float xv[16];
            #pragma unroll
            for (int q = 0; q < 4; ++q)
                *(f32x4*)&xv[q * 4] = *(const f32x4*)(x0s + r * 16 + q * 4);
            const size_t orow = (size_t)(rowBase + r) * N_DIM + colBase;
            #pragma unroll
            for (int n = 0; n < 4; ++n) {
                float y1 = 0.f, s2 = 0.f;
                #pragma unroll
                for (int k = 0; k < 16; ++k) {
                    float xk = xv[k];
                    float wk = wv[n][k];
                    float xx = xk * xk;
                    float ww = wk * wk;
                    y1 = fmaf(xk, wk, y1);
                    s2 = fmaf(xx, ww, s2);
                }
                float t = fabsf(y1) / sqrtf(s2 * 0.0625f);
                float v = (t < TAU32) ? 0.0f : (acc[m][n][j] + bv[n]);
                out[orow + wc * 64 + n * 16 + lr] = v;
            }
        }
    }
}

extern "C" void kernel_launch(void* const* d_in, const int* in_sizes, int n_in,
                              void* d_out, int out_size, void* d_ws, size_t ws_size,
                              hipStream_t stream) {
    const float* x    = (const float*)d_in[0];
    const float* W    = (const float*)d_in[1];
    const float* bias = (const float*)d_in[2];
    float* out = (float*)d_out;

    const size_t needA = (size_t)M_DIM * K_DIM * 2;   // 64 MB
    const size_t needB = (size_t)N_DIM * K_DIM * 2;   // 32 MB

    if (ws_size >= needA + needB) {
        unsigned short* xb = (unsigned short*)d_ws;
        unsigned short* wb = (unsigned short*)((char*)d_ws + needA);
        cvt_f32_to_bf16<<<2048, 256, 0, stream>>>(
            (const float4*)x, (uint2*)xb, (M_DIM * K_DIM) / 4);
        cvt_f32_to_bf16<<<2048, 256, 0, stream>>>(
            (const float4*)W, (uint2*)wb, (N_DIM * K_DIM) / 4);
        dim3 grid((M_DIM / 256) * (N_DIM / 256));     // 512 blocks, 1-D
        gemm_masked8<<<grid, 512, 0, stream>>>(xb, wb, x, W, bias, out);
    } else {
        dim3 grid(N_DIM / 128, M_DIM / 128);
        gemm_masked_fb<<<grid, 256, 0, stream>>>(x, W, bias, out);
    }
}